// Round 8
// baseline (364.649 us; speedup 1.0000x reference)
//
#include <hip/hip_runtime.h>
#include <stdint.h>

typedef _Float16 f16;
typedef __attribute__((ext_vector_type(8)))  _Float16 f16x8;
typedef __attribute__((ext_vector_type(4)))  float    f32x4;

#define NSTEPS 79
#define CDIM   256
#define ROWS   32                // rows per block (2 m-tiles of 16)
#define NKS    8                 // h k-steps (8 x K=32)
#define NT     4                 // n-tiles per wave -> 64 cols/wave
#define MTSZ   9216              // bytes per m-tile per plane: 9 ksteps * 1024
#define PLANE  (2*MTSZ)          // per plane (2 m-tiles) = 18432
#define BUF    (2*PLANE)         // one h buffer (hi+lo planes) = 36864

// ---------------------------------------------------------------------------
// 256 blocks x 512 threads (8 waves, 1 block/CU). Wave w: m-tile wr = w>>2,
// col group wc = w&3 (64 cols). Per-wave B1[4][8] = 128 VGPR; per-CU LDS
// A-read traffic halved vs R6 (144 KB/step: 8 waves x 18 reads).
// h: DOUBLE-BUFFERED, one barrier/step. Two f16 planes per buffer
// (hi = f16(h), lo = f16(h-hi)), FRAGMENT-MAJOR per m-tile:
//   off(plane,mt,ks,dl,i) = plane*PLANE + mt*MTSZ + ks*1024 + swz(dl,ks)*16 + i*2
//   chunk dl holds A[m = dl&15][k = ks*32 + (dl>>4)*8 + i]
//   swz(dl,ks) = dl ^ ((dl>>3)&7) ^ (ks&7)
// value h[m][n]: ks=n>>5, kgroup=(n>>3)&3, i=n&7, dl=m+16*kgroup.
// kstep 8 = augmented x tile, Baug = [Wx_hi(r0-3); Wx_lo(r4-7)]:
//   hi-plane aug A = [x_hi | x_hi] -> x_hi*Wx_hi + x_hi*Wx_lo
//   lo-plane aug A = [x_lo | 0   ] -> x_lo*Wx_hi     (no lo*lo term)
//
// R5-R7 lesson: __launch_bounds__(_,2) lets the allocator chase 4 waves/EU,
// cap VGPRs at 64/128 and SPILL (83-183 MB scratch WRITE traffic).
// amdgpu_waves_per_eu(2,2) pins occupancy -> full 256-reg budget, no spill.
// Spill signature to watch: WRITE_SIZE >> 30 MB.
// ---------------------------------------------------------------------------

// MFMA 16x16x32_f16 layout (verified R1):
//   A: lane l holds A[m = l&15][k = 8*(l>>4)+i]
//   B: lane l holds B[k = 8*(l>>4)+i][n = l&15]
//   C/D: lane l, reg r -> C[row = (l>>4)*4 + r][col = l&15]

__global__
__attribute__((amdgpu_waves_per_eu(2, 2)))
__launch_bounds__(512)
void rnn_fused(
    const float* __restrict__ x0p, const float* __restrict__ x1p,
    const float* __restrict__ x2p, const float* __restrict__ x3p,
    const float* __restrict__ Wx,  const float* __restrict__ Wh,
    const float* __restrict__ brnn,const float* __restrict__ Wd,
    const float* __restrict__ bd,  float* __restrict__ out)
{
    __shared__ __align__(16) char hb[2*BUF];   // 73728 B (double-buffered h)

    const int tid  = (int)threadIdx.x;
    const int w    = tid >> 6;        // wave 0..7
    const int wr   = w >> 2;          // m-tile 0/1 (rows wr*16 .. +16)
    const int wc   = w & 3;           // col group (cols wc*64 .. +64)
    const int l    = tid & 63;
    const int ln16 = l & 15;
    const int kgl  = l >> 4;          // 0..3
    const int r0   = (int)blockIdx.x * ROWS;
    const int n0   = wc * 64;

    // -------- Wh-hi fragments (4 n-tiles) + augmented Wx fragments --------
    f16x8 B1[NT][NKS];          // 128 VGPR; reused for Wd after the recurrence
    f16x8 Baug[NT];
    float bias[NT];
    #pragma unroll
    for (int nt = 0; nt < NT; ++nt) {
        const int n = n0 + nt*16 + ln16;
        #pragma unroll
        for (int ks = 0; ks < NKS; ++ks) {
            const int k0 = ks*32 + kgl*8;
            f16x8 b;
            #pragma unroll
            for (int i = 0; i < 8; ++i)
                b[i] = (f16)Wh[(size_t)(k0 + i)*CDIM + n];
            B1[nt][ks] = b;
        }
        f16x8 e;
        #pragma unroll
        for (int i = 0; i < 8; ++i) e[i] = (f16)0.0f;
        if (kgl == 0) {
            #pragma unroll
            for (int i = 0; i < 4; ++i) {
                float wv = Wx[i*CDIM + n];
                f16 whi = (f16)wv;
                e[i]   = whi;                       // rows 0-3: Wx_hi
                e[i+4] = (f16)(wv - (float)whi);    // rows 4-7: Wx_lo
            }
        }
        Baug[nt] = e;
        bias[nt] = brnn[n];
    }

    // -------- precomputed LDS addresses --------
    const unsigned rba = (unsigned)(wr*MTSZ) + (unsigned)((l ^ ((l >> 3) & 7)) * 16);
    int waddr[NT][4];
    #pragma unroll
    for (int nt = 0; nt < NT; ++nt) {
        const int n      = n0 + nt*16 + ln16;
        const int ksw    = n >> 5;
        const int kgroup = (n >> 3) & 3;
        const int i      = n & 7;
        #pragma unroll
        for (int r = 0; r < 4; ++r) {
            const int mr = kgl*4 + r;
            const int dl = mr + 16*kgroup;
            const int sw = dl ^ ((dl >> 3) & 7) ^ (ksw & 7);
            waddr[nt][r] = wr*MTSZ + ksw*1024 + sw*16 + i*2;
        }
    }
    // x writer: tid<128 -> (row mfull = tid>>2, feature f = tid&3)
    const int  mfull = tid >> 2;
    const int  xf    = tid & 3;
    const int  xmt   = mfull >> 4;
    const int  xm    = mfull & 15;
    const int  xbase = xmt*MTSZ + NKS*1024 + (xm ^ ((xm >> 3) & 7))*16 + xf*2;
    const float* xptr = (xf == 0) ? x0p : (xf == 1) ? x1p : (xf == 2) ? x2p : x3p;
    const bool xwriter = (tid < 128);

    // -------- init: zero both buffers; write aug(0) into buffer 0 --------
    for (int i = tid; i < (2*BUF)/4; i += 512)
        ((uint32_t*)hb)[i] = 0u;
    float xv = 0.f;
    if (xwriter) xv = xptr[(size_t)(r0 + mfull)*NSTEPS + (NSTEPS - 1)];  // t=0 (reversed)
    __syncthreads();          // zeros done before aug write
    if (xwriter) {
        f16 hi = (f16)xv;
        f16 lo = (f16)(xv - (float)hi);
        *(f16*)(hb + xbase)         = hi;   // hi-plane k'=f
        *(f16*)(hb + xbase + 8)     = hi;   // hi-plane k'=4+f (dup)
        *(f16*)(hb + xbase + PLANE) = lo;   // lo-plane k'=f
    }
    __syncthreads();

    // -------- recurrence: ONE barrier per step (double-buffered) --------
    #pragma unroll 1
    for (int t = 0; t < NSTEPS; ++t) {
        const char* cbuf = hb + (t & 1)*BUF;
        char*       nbuf = hb + ((t + 1) & 1)*BUF;

        // prefetch next step's x early (latency hides under read+MFMA phase)
        float xnext = 0.f;
        if (xwriter && t + 1 < NSTEPS)
            xnext = xptr[(size_t)(r0 + mfull)*NSTEPS + (NSTEPS - 2 - t)];

        f32x4 acc[NT];
        #pragma unroll
        for (int nt = 0; nt < NT; ++nt) {
            f32x4 vb = {bias[nt], bias[nt], bias[nt], bias[nt]};
            acc[nt] = vb;
        }

        #pragma unroll
        for (int ks = 0; ks < NKS; ++ks) {
            const unsigned ra = (unsigned)(ks*1024) + ((unsigned)rba ^ (unsigned)((ks & 7) << 4));
            f16x8 a1 = *(const f16x8*)(cbuf + ra);            // hi
            f16x8 a2 = *(const f16x8*)(cbuf + PLANE + ra);    // lo
            #pragma unroll
            for (int nt = 0; nt < NT; ++nt)
                acc[nt] = __builtin_amdgcn_mfma_f32_16x16x32_f16(a1, B1[nt][ks], acc[nt], 0, 0, 0);
            #pragma unroll
            for (int nt = 0; nt < NT; ++nt)
                acc[nt] = __builtin_amdgcn_mfma_f32_16x16x32_f16(a2, B1[nt][ks], acc[nt], 0, 0, 0);
        }
        {   // augmented x k-step (ks=8 -> ks&7=0, no xor term)
            const unsigned ra = (unsigned)(NKS*1024) + rba;
            f16x8 a1 = *(const f16x8*)(cbuf + ra);
            f16x8 a2 = *(const f16x8*)(cbuf + PLANE + ra);
            #pragma unroll
            for (int nt = 0; nt < NT; ++nt)
                acc[nt] = __builtin_amdgcn_mfma_f32_16x16x32_f16(a1, Baug[nt], acc[nt], 0, 0, 0);
            #pragma unroll
            for (int nt = 0; nt < NT; ++nt)
                acc[nt] = __builtin_amdgcn_mfma_f32_16x16x32_f16(a2, Baug[nt], acc[nt], 0, 0, 0);
        }

        // writes go to the OTHER buffer -> no barrier needed before them
        if (xwriter && t + 1 < NSTEPS) {
            f16 hi = (f16)xnext;
            f16 lo = (f16)(xnext - (float)hi);
            *(f16*)(nbuf + xbase)         = hi;
            *(f16*)(nbuf + xbase + 8)     = hi;
            *(f16*)(nbuf + xbase + PLANE) = lo;
        }
        #pragma unroll
        for (int nt = 0; nt < NT; ++nt) {
            #pragma unroll
            for (int r = 0; r < 4; ++r) {
                float v = acc[nt][r];
                v = v > 0.f ? v : 0.f;
                f16 hi = (f16)v;
                f16 lo = (f16)(v - (float)hi);
                *(f16*)(nbuf + waddr[nt][r])         = hi;
                *(f16*)(nbuf + waddr[nt][r] + PLANE) = lo;
            }
        }
        __syncthreads();   // h(t+1)/aug(t+1) visible; cbuf free next step
    }

    // -------- final dense: out = relu(h @ Wd + b_d), reuse B1 regs --------
    // NSTEPS odd -> final h is in buffer 1
    #pragma unroll
    for (int nt = 0; nt < NT; ++nt) {
        const int n = n0 + nt*16 + ln16;
        #pragma unroll
        for (int ks = 0; ks < NKS; ++ks) {
            const int k0 = ks*32 + kgl*8;
            f16x8 b;
            #pragma unroll
            for (int i = 0; i < 8; ++i)
                b[i] = (f16)Wd[(size_t)(k0 + i)*CDIM + n];
            B1[nt][ks] = b;
        }
    }
    {
        const char* rp = hb + BUF;
        f32x4 acc[NT];
        #pragma unroll
        for (int nt = 0; nt < NT; ++nt) {
            float b = bd[n0 + nt*16 + ln16];
            f32x4 vb = {b, b, b, b};
            acc[nt] = vb;
        }
        #pragma unroll
        for (int ks = 0; ks < NKS; ++ks) {
            const unsigned ra = (unsigned)(ks*1024) + ((unsigned)rba ^ (unsigned)((ks & 7) << 4));
            f16x8 a1 = *(const f16x8*)(rp + ra);
            f16x8 a2 = *(const f16x8*)(rp + PLANE + ra);
            #pragma unroll
            for (int nt = 0; nt < NT; ++nt)
                acc[nt] = __builtin_amdgcn_mfma_f32_16x16x32_f16(a1, B1[nt][ks], acc[nt], 0, 0, 0);
            #pragma unroll
            for (int nt = 0; nt < NT; ++nt)
                acc[nt] = __builtin_amdgcn_mfma_f32_16x16x32_f16(a2, B1[nt][ks], acc[nt], 0, 0, 0);
        }
        #pragma unroll
        for (int nt = 0; nt < NT; ++nt) {
            const int n = n0 + nt*16 + ln16;
            #pragma unroll
            for (int r = 0; r < 4; ++r) {
                const int mr = wr*16 + kgl*4 + r;
                float v = acc[nt][r];
                v = v > 0.f ? v : 0.f;
                out[(size_t)(r0 + mr)*CDIM + n] = v;
            }
        }
    }
}

extern "C" void kernel_launch(void* const* d_in, const int* in_sizes, int n_in,
                              void* d_out, int out_size, void* d_ws, size_t ws_size,
                              hipStream_t stream)
{
    (void)in_sizes; (void)n_in; (void)out_size; (void)d_ws; (void)ws_size;
    const float* x0 = (const float*)d_in[0];
    const float* x1 = (const float*)d_in[1];
    const float* x2 = (const float*)d_in[2];
    const float* x3 = (const float*)d_in[3];
    const float* Wx = (const float*)d_in[4];
    const float* Wh = (const float*)d_in[5];
    const float* br = (const float*)d_in[6];
    const float* Wd = (const float*)d_in[7];
    const float* bd = (const float*)d_in[8];
    float* out = (float*)d_out;

    rnn_fused<<<dim3(8192 / ROWS), dim3(512), 0, stream>>>(
        x0, x1, x2, x3, Wx, Wh, br, Wd, bd, out);
}

// Round 9
// 171.841 us; speedup vs baseline: 2.1220x; 2.1220x over previous
//
#include <hip/hip_runtime.h>
#include <stdint.h>

typedef _Float16 f16;
typedef __attribute__((ext_vector_type(8)))  _Float16 f16x8;
typedef __attribute__((ext_vector_type(4)))  float    f32x4;

#define NSTEPS 79
#define CDIM   256
#define ROWS   32                // rows per block (2 m-tiles of 16)
#define NKS    8                 // h k-steps (8 x K=32)
#define MTSZ   9216              // bytes per m-tile: 9 ksteps * 64 chunks * 16B
#define BUF    (2*MTSZ)          // one h buffer (2 m-tiles) = 18432 B

// ---------------------------------------------------------------------------
// SINGLE-PLANE f16 h (R9): the h lo-plane is dropped. Error calibration:
// dropping the Wh-lo plane (R3->R4) added +0.0078 absmax; the A-side h-lo
// drop is magnitude-symmetric (both RTE 2^-12/step) -> predicted total
// ~0.03 vs 0.066 threshold. Halves LDS reads, MFMAs, h-writes, epilogue.
//
// 256 blocks x 512 threads (8 waves, 1 block/CU). Wave w owns cols
// [w*32, w*32+32) (2 n-tiles) for ALL 32 rows (2 m-tiles).
// h: DOUBLE-BUFFERED, ONE barrier/step. FRAGMENT-MAJOR per m-tile:
//   off(mt,ks,dl,i) = mt*MTSZ + ks*1024 + swz(dl,ks)*16 + i*2
//   chunk dl holds A[m = dl&15][k = ks*32 + (dl>>4)*8 + i]
//   swz(dl,ks) = dl ^ ((dl>>3)&7) ^ (ks&7)
// value h[m][n]: ks=n>>5, kgroup=(n>>3)&3, i=n&7, dl=(m&15)+16*kgroup, mt=m>>4.
// kstep 8 = augmented x tile: A = [x_hi(k'0-3) | x_lo(k'4-7)],
//   Baug = [Wx_hi; Wx_hi] -> x_hi*Wx_hi + x_lo*Wx_hi
//   (x_hi*Wx_lo and x_lo*Wx_lo dropped: ~1.5e-4/step, negligible).
// x prefetched from global each step (no LDS staging of the series).
//
// REGALLOC LAW (R5-R8 measured): allocator grants cap/2 arch VGPRs
// ((256,1)->256, (512,2)->128, (512,4)->64); rest is the AGPR half.
// Demand here ~121 <= 128 -> no spill. Spill signature: WRITE_SIZE >> 30MB.
// ---------------------------------------------------------------------------

// MFMA 16x16x32_f16 layout (verified R1):
//   A: lane l holds A[m = l&15][k = 8*(l>>4)+i]
//   B: lane l holds B[k = 8*(l>>4)+i][n = l&15]
//   C/D: lane l, reg r -> C[row = (l>>4)*4 + r][col = l&15]

__global__ __launch_bounds__(512, 2) void rnn_fused(
    const float* __restrict__ x0p, const float* __restrict__ x1p,
    const float* __restrict__ x2p, const float* __restrict__ x3p,
    const float* __restrict__ Wx,  const float* __restrict__ Wh,
    const float* __restrict__ brnn,const float* __restrict__ Wd,
    const float* __restrict__ bd,  float* __restrict__ out)
{
    __shared__ __align__(16) char hb[2*BUF];   // 36864 B (double-buffered h)

    const int tid  = (int)threadIdx.x;
    const int w    = tid >> 6;        // wave 0..7 -> cols [w*32, w*32+32)
    const int l    = tid & 63;
    const int ln16 = l & 15;
    const int kgl  = l >> 4;          // 0..3
    const int r0   = (int)blockIdx.x * ROWS;
    const int n0   = w * 32;

    // -------- Wh-hi fragments (2 n-tiles) + augmented Wx fragment --------
    f16x8 B1[2][NKS];          // 64 VGPR; reused for Wd after the recurrence
    f16x8 Baug[2];
    float bias[2];
    #pragma unroll
    for (int nt = 0; nt < 2; ++nt) {
        const int n = n0 + nt*16 + ln16;
        #pragma unroll
        for (int ks = 0; ks < NKS; ++ks) {
            const int k0 = ks*32 + kgl*8;
            f16x8 b;
            #pragma unroll
            for (int i = 0; i < 8; ++i)
                b[i] = (f16)Wh[(size_t)(k0 + i)*CDIM + n];
            B1[nt][ks] = b;
        }
        f16x8 e;
        #pragma unroll
        for (int i = 0; i < 8; ++i) e[i] = (f16)0.0f;
        if (kgl == 0) {
            // k' = i: rows 0-3 meet x_hi, rows 4-7 meet x_lo; both need Wx_hi
            #pragma unroll
            for (int i = 0; i < 4; ++i) {
                f16 whi = (f16)Wx[i*CDIM + n];
                e[i]   = whi;
                e[i+4] = whi;
            }
        }
        Baug[nt] = e;
        bias[nt] = brnn[n];
    }

    // -------- precomputed LDS addresses --------
    const unsigned rba = (unsigned)((l ^ ((l >> 3) & 7)) * 16);   // read base (within m-tile)
    int waddr[2][4];   // write addr for (nt, r), m-tile 0; + mt*MTSZ for m-tile 1
    #pragma unroll
    for (int nt = 0; nt < 2; ++nt) {
        const int n      = n0 + nt*16 + ln16;
        const int ksw    = n >> 5;
        const int kgroup = (n >> 3) & 3;
        const int i      = n & 7;
        #pragma unroll
        for (int r = 0; r < 4; ++r) {
            const int mr = kgl*4 + r;           // row within m-tile
            const int dl = mr + 16*kgroup;
            const int sw = dl ^ ((dl >> 3) & 7) ^ (ksw & 7);
            waddr[nt][r] = ksw*1024 + sw*16 + i*2;
        }
    }
    // x writer: tid<128 -> (row mfull = tid>>2, feature f = tid&3)
    const int  mfull = tid >> 2;
    const int  xf    = tid & 3;
    const int  xmt   = mfull >> 4;
    const int  xm    = mfull & 15;
    const int  xbase = xmt*MTSZ + NKS*1024 + (xm ^ ((xm >> 3) & 7))*16 + xf*2;
    const float* xptr = (xf == 0) ? x0p : (xf == 1) ? x1p : (xf == 2) ? x2p : x3p;
    const bool xwriter = (tid < 128);

    // -------- init: zero both buffers; write aug(0) into buffer 0 --------
    for (int i = tid; i < (2*BUF)/4; i += 512)
        ((uint32_t*)hb)[i] = 0u;
    float xv = 0.f;
    if (xwriter) xv = xptr[(size_t)(r0 + mfull)*NSTEPS + (NSTEPS - 1)];  // t=0 (reversed)
    __syncthreads();          // zeros done before aug write
    if (xwriter) {
        f16 hi = (f16)xv;
        f16 lo = (f16)(xv - (float)hi);
        *(f16*)(hb + xbase)     = hi;   // k' = xf     : x_hi
        *(f16*)(hb + xbase + 8) = lo;   // k' = 4 + xf : x_lo
    }
    __syncthreads();

    // -------- recurrence: ONE barrier per step (double-buffered) --------
    #pragma unroll 1
    for (int t = 0; t < NSTEPS; ++t) {
        const char* cbuf = hb + (t & 1)*BUF;
        char*       nbuf = hb + ((t + 1) & 1)*BUF;

        // prefetch next step's x early (latency hides under read+MFMA phase)
        float xnext = 0.f;
        if (xwriter && t + 1 < NSTEPS)
            xnext = xptr[(size_t)(r0 + mfull)*NSTEPS + (NSTEPS - 2 - t)];

        f32x4 acc00 = {bias[0], bias[0], bias[0], bias[0]};   // mt0, nt0
        f32x4 acc01 = {bias[1], bias[1], bias[1], bias[1]};   // mt0, nt1
        f32x4 acc10 = {bias[0], bias[0], bias[0], bias[0]};   // mt1, nt0
        f32x4 acc11 = {bias[1], bias[1], bias[1], bias[1]};   // mt1, nt1

        #pragma unroll
        for (int ks = 0; ks < NKS; ++ks) {
            const unsigned ra = (unsigned)(ks*1024) + (rba ^ (unsigned)((ks & 7) << 4));
            f16x8 a0 = *(const f16x8*)(cbuf + ra);            // m-tile 0
            f16x8 a1 = *(const f16x8*)(cbuf + MTSZ + ra);     // m-tile 1
            acc00 = __builtin_amdgcn_mfma_f32_16x16x32_f16(a0, B1[0][ks], acc00, 0, 0, 0);
            acc01 = __builtin_amdgcn_mfma_f32_16x16x32_f16(a0, B1[1][ks], acc01, 0, 0, 0);
            acc10 = __builtin_amdgcn_mfma_f32_16x16x32_f16(a1, B1[0][ks], acc10, 0, 0, 0);
            acc11 = __builtin_amdgcn_mfma_f32_16x16x32_f16(a1, B1[1][ks], acc11, 0, 0, 0);
        }
        {   // augmented x k-step (ks=8 -> ks&7=0, no xor term)
            const unsigned ra = (unsigned)(NKS*1024) + rba;
            f16x8 a0 = *(const f16x8*)(cbuf + ra);
            f16x8 a1 = *(const f16x8*)(cbuf + MTSZ + ra);
            acc00 = __builtin_amdgcn_mfma_f32_16x16x32_f16(a0, Baug[0], acc00, 0, 0, 0);
            acc01 = __builtin_amdgcn_mfma_f32_16x16x32_f16(a0, Baug[1], acc01, 0, 0, 0);
            acc10 = __builtin_amdgcn_mfma_f32_16x16x32_f16(a1, Baug[0], acc10, 0, 0, 0);
            acc11 = __builtin_amdgcn_mfma_f32_16x16x32_f16(a1, Baug[1], acc11, 0, 0, 0);
        }

        // writes go to the OTHER buffer -> no barrier needed before them
        if (xwriter && t + 1 < NSTEPS) {
            f16 hi = (f16)xnext;
            f16 lo = (f16)(xnext - (float)hi);
            *(f16*)(nbuf + xbase)     = hi;
            *(f16*)(nbuf + xbase + 8) = lo;
        }
        #pragma unroll
        for (int r = 0; r < 4; ++r) {
            float v;
            v = acc00[r]; v = v > 0.f ? v : 0.f;
            *(f16*)(nbuf + waddr[0][r])        = (f16)v;
            v = acc01[r]; v = v > 0.f ? v : 0.f;
            *(f16*)(nbuf + waddr[1][r])        = (f16)v;
            v = acc10[r]; v = v > 0.f ? v : 0.f;
            *(f16*)(nbuf + waddr[0][r] + MTSZ) = (f16)v;
            v = acc11[r]; v = v > 0.f ? v : 0.f;
            *(f16*)(nbuf + waddr[1][r] + MTSZ) = (f16)v;
        }
        __syncthreads();   // h(t+1)/aug(t+1) visible; cbuf free next step
    }

    // -------- final dense: out = relu(h @ Wd + b_d), reuse B1 regs --------
    // NSTEPS odd -> final h is in buffer 1
    #pragma unroll
    for (int nt = 0; nt < 2; ++nt) {
        const int n = n0 + nt*16 + ln16;
        #pragma unroll
        for (int ks = 0; ks < NKS; ++ks) {
            const int k0 = ks*32 + kgl*8;
            f16x8 b;
            #pragma unroll
            for (int i = 0; i < 8; ++i)
                b[i] = (f16)Wd[(size_t)(k0 + i)*CDIM + n];
            B1[nt][ks] = b;
        }
    }
    {
        const char* rp = hb + BUF;
        const float bd0 = bd[n0 + ln16];
        const float bd1 = bd[n0 + 16 + ln16];
        f32x4 acc00 = {bd0, bd0, bd0, bd0};
        f32x4 acc01 = {bd1, bd1, bd1, bd1};
        f32x4 acc10 = {bd0, bd0, bd0, bd0};
        f32x4 acc11 = {bd1, bd1, bd1, bd1};
        #pragma unroll
        for (int ks = 0; ks < NKS; ++ks) {
            const unsigned ra = (unsigned)(ks*1024) + (rba ^ (unsigned)((ks & 7) << 4));
            f16x8 a0 = *(const f16x8*)(rp + ra);
            f16x8 a1 = *(const f16x8*)(rp + MTSZ + ra);
            acc00 = __builtin_amdgcn_mfma_f32_16x16x32_f16(a0, B1[0][ks], acc00, 0, 0, 0);
            acc01 = __builtin_amdgcn_mfma_f32_16x16x32_f16(a0, B1[1][ks], acc01, 0, 0, 0);
            acc10 = __builtin_amdgcn_mfma_f32_16x16x32_f16(a1, B1[0][ks], acc10, 0, 0, 0);
            acc11 = __builtin_amdgcn_mfma_f32_16x16x32_f16(a1, B1[1][ks], acc11, 0, 0, 0);
        }
        #pragma unroll
        for (int r = 0; r < 4; ++r) {
            const int mr = kgl*4 + r;
            float v;
            v = acc00[r]; out[(size_t)(r0 + mr)*CDIM      + (n0 + ln16)]      = v > 0.f ? v : 0.f;
            v = acc01[r]; out[(size_t)(r0 + mr)*CDIM      + (n0 + 16 + ln16)] = v > 0.f ? v : 0.f;
            v = acc10[r]; out[(size_t)(r0 + 16 + mr)*CDIM + (n0 + ln16)]      = v > 0.f ? v : 0.f;
            v = acc11[r]; out[(size_t)(r0 + 16 + mr)*CDIM + (n0 + 16 + ln16)] = v > 0.f ? v : 0.f;
        }
    }
}

extern "C" void kernel_launch(void* const* d_in, const int* in_sizes, int n_in,
                              void* d_out, int out_size, void* d_ws, size_t ws_size,
                              hipStream_t stream)
{
    (void)in_sizes; (void)n_in; (void)out_size; (void)d_ws; (void)ws_size;
    const float* x0 = (const float*)d_in[0];
    const float* x1 = (const float*)d_in[1];
    const float* x2 = (const float*)d_in[2];
    const float* x3 = (const float*)d_in[3];
    const float* Wx = (const float*)d_in[4];
    const float* Wh = (const float*)d_in[5];
    const float* br = (const float*)d_in[6];
    const float* Wd = (const float*)d_in[7];
    const float* bd = (const float*)d_in[8];
    float* out = (float*)d_out;

    rnn_fused<<<dim3(8192 / ROWS), dim3(512), 0, stream>>>(
        x0, x1, x2, x3, Wx, Wh, br, Wd, bd, out);
}